// Round 1
// baseline (31300.690 us; speedup 1.0000x reference)
//
#include <hip/hip_runtime.h>
#include <hip/hip_bf16.h>

typedef __attribute__((ext_vector_type(8))) short short8;
typedef __attribute__((ext_vector_type(4))) float f32x4;

#define B_ 256
#define S_ 128
#define I_ 256
#define H_ 2048
#define O_ 256

__device__ __forceinline__ unsigned short f2bf(float f) {
  union { float f; unsigned u; } v; v.f = f;
  unsigned u = v.u;
  unsigned r = (u + 0x7FFFu + ((u >> 16) & 1u)) >> 16;  // RNE
  return (unsigned short)r;
}
__device__ __forceinline__ float bf2f(unsigned short u) {
  union { unsigned u; float f; } v; v.u = ((unsigned)u) << 16;
  return v.f;
}
__device__ __forceinline__ short8 cvt8(const float* p) {
  const f32x4* q = (const f32x4*)p;
  f32x4 a = q[0], b = q[1];
  short8 r;
  r[0]=(short)f2bf(a[0]); r[1]=(short)f2bf(a[1]); r[2]=(short)f2bf(a[2]); r[3]=(short)f2bf(a[3]);
  r[4]=(short)f2bf(b[0]); r[5]=(short)f2bf(b[1]); r[6]=(short)f2bf(b[2]); r[7]=(short)f2bf(b[3]);
  return r;
}

// ---------------------------------------------------------------------------
// Pack W_rec (f32 [H][H]) into MFMA B-fragment-major bf16:
// w_frag[nb][kt][lane][j] = W_rec[16*nb + (lane&15)][32*kt + 8*(lane>>4) + j]
// ---------------------------------------------------------------------------
__global__ void __launch_bounds__(256) prep_w(const float* __restrict__ W_rec,
                                              short8* __restrict__ w_frag) {
  int idx = blockIdx.x * 256 + threadIdx.x;      // 0 .. 128*64*64-1
  int l  = idx & 63;
  int kt = (idx >> 6) & 63;
  int nb = idx >> 12;
  int n  = nb * 16 + (l & 15);
  int k0 = kt * 32 + ((l >> 4) * 8);
  w_frag[idx] = cvt8(W_rec + (size_t)n * H_ + k0);
}

// ---------------------------------------------------------------------------
// inp[s][b][h] = x[b][s][:] @ W_in[h][:] + b_in[h], stored bf16 in the
// ownership-linear fragment layout the main kernel consumes:
// inp_f[(s*256 + bid)*256 + tid][j]   (bid = rh*8+rb, same tiling as main)
// ---------------------------------------------------------------------------
__global__ void __launch_bounds__(256) inp_kernel(const float* __restrict__ x,
                                                  const float* __restrict__ W_in,
                                                  const float* __restrict__ b_in,
                                                  short8* __restrict__ inp_f) {
  int bid = blockIdx.x;             // 0 .. 128*256-1
  int s   = bid >> 8;
  int sub = bid & 255;
  int rh  = sub >> 3, rb = sub & 7;
  int tid = threadIdx.x;
  int w = tid >> 6, l = tid & 63;
  int wr = w >> 1, wc = w & 1;

  int brow = 32 * rb + 16 * wr + (l & 15);
  int h0   = 64 * rh + 32 * wc + (l & 15);
  const float* xp  = x   + ((size_t)brow * S_ + s) * I_ + ((l >> 4) * 8);
  const float* wp0 = W_in + (size_t)h0 * I_        + ((l >> 4) * 8);
  const float* wp1 = W_in + (size_t)(h0 + 16) * I_ + ((l >> 4) * 8);

  f32x4 acc0 = {0.f,0.f,0.f,0.f}, acc1 = {0.f,0.f,0.f,0.f};
#pragma unroll
  for (int kt = 0; kt < 8; ++kt) {
    short8 af  = cvt8(xp  + kt * 32);
    short8 bf0 = cvt8(wp0 + kt * 32);
    short8 bf1 = cvt8(wp1 + kt * 32);
    acc0 = __builtin_amdgcn_mfma_f32_16x16x32_bf16(af, bf0, acc0, 0, 0, 0);
    acc1 = __builtin_amdgcn_mfma_f32_16x16x32_bf16(af, bf1, acc1, 0, 0, 0);
  }
  short8 outv;
#pragma unroll
  for (int j = 0; j < 8; ++j) {
    int nb = j >> 2, r = j & 3;
    int col = 64 * rh + 32 * wc + 16 * nb + (l & 15);
    float v = ((nb ? acc1 : acc0)[r]) + b_in[col];
    outv[j] = (short)f2bf(v);
  }
  inp_f[(size_t)bid * 256 + tid] = outv;
}

// ---------------------------------------------------------------------------
// Persistent cooperative RNN kernel. 256 wgs x 256 thr, 1 wg/CU.
// wg tile: 32 batch-rows (rb = bid&7) x 64 hidden-cols (rh = bid>>3).
// Barrier only among the 32 wgs sharing rb (consumers/producers of rows).
// h, RK4 accumulator, eval point live in registers; the all-gathered
// activation goes through double-buffered fragment-major bf16 in ws.
// ---------------------------------------------------------------------------
__device__ __forceinline__ void rb_barrier(unsigned* __restrict__ cg, unsigned epoch) {
  __threadfence();          // release all this block's prior stores (agent)
  __syncthreads();
  if (threadIdx.x == 0) {
    __hip_atomic_fetch_add(cg, 1u, __ATOMIC_RELEASE, __HIP_MEMORY_SCOPE_AGENT);
    unsigned target = epoch * 32u;
    while (__hip_atomic_load(cg, __ATOMIC_RELAXED, __HIP_MEMORY_SCOPE_AGENT) < target) {
      __builtin_amdgcn_s_sleep(1);
    }
    __threadfence();        // acquire
  }
  __syncthreads();
}

__global__ void __launch_bounds__(256, 1) rnn_main(
    const short8* __restrict__ w_frag,
    const short8* __restrict__ inp_f,
    unsigned short* __restrict__ a16_0,
    unsigned short* __restrict__ a16_1,
    float* __restrict__ h_out,
    unsigned* __restrict__ cnt)
{
  const int bid = blockIdx.x;
  const int rb = bid & 7, rh = bid >> 3;
  const int tid = threadIdx.x;
  const int w = tid >> 6, l = tid & 63;
  const int wr = w >> 1, wc = w & 1;
  const int mb_g = 2 * rb + wr;            // 16-row A block this wave owns
  const int nb0  = 4 * rh + 2 * wc;        // first of two 16-col B blocks

  const short8* Bp0 = w_frag + (size_t)nb0 * 64 * 64 + l;
  const short8* Bp1 = w_frag + (size_t)(nb0 + 1) * 64 * 64 + l;
  const int aoff = mb_g * 64 * 64 + l;
  const short8* A0 = (const short8*)a16_0 + aoff;
  const short8* A1 = (const short8*)a16_1 + aoff;
  const int ktw = 2 * rh + wc;             // kt block our cols map to

  // Write offsets (ushort units) of this thread's 8 owned elements in the
  // fragment-major activation buffer (same for both buffers).
  int woff[8];
#pragma unroll
  for (int j = 0; j < 8; ++j) {
    int nb = j >> 2, r = j & 3;
    int lp = (2 * nb + ((l & 15) >> 3)) * 16 + ((l >> 4) * 4 + r);
    woff[j] = ((mb_g * 64 + ktw) * 64 + lp) * 8 + (l & 7);
  }

  float h[8], hacc[8], an[8];
#pragma unroll
  for (int j = 0; j < 8; ++j) { h[j] = 0.f; hacc[j] = 0.f; an[j] = 0.f; }
  // h0 = 0: publish zeros into buffer 0 (read by first stage)
#pragma unroll
  for (int j = 0; j < 8; ++j) a16_0[woff[j]] = 0;

  unsigned* cg = cnt + rb * 32;            // 128B-separated counters
  rb_barrier(cg, 1);

#pragma unroll 1
  for (int s = 0; s < S_; ++s) {
    short8 inpv = inp_f[((size_t)s * 256 + bid) * 256 + tid];
#pragma unroll
    for (int st = 0; st < 4; ++st) {
      const short8* Ap = (st & 1) ? A1 : A0;          // read buf[st&1]
      unsigned short* WB = (st & 1) ? a16_0 : a16_1;  // write the other
      f32x4 acc0 = {0.f,0.f,0.f,0.f}, acc1 = {0.f,0.f,0.f,0.f};

      // K loop over 64 kt blocks, depth-4 prefetch, all indices static.
      short8 a_[4], b0_[4], b1_[4];
#pragma unroll
      for (int i = 0; i < 4; ++i) { a_[i] = Ap[i*64]; b0_[i] = Bp0[i*64]; b1_[i] = Bp1[i*64]; }
#pragma unroll
      for (int kt = 0; kt < 64; kt += 4) {
#pragma unroll
        for (int u = 0; u < 4; ++u) {
          acc0 = __builtin_amdgcn_mfma_f32_16x16x32_bf16(a_[u], b0_[u], acc0, 0, 0, 0);
          acc1 = __builtin_amdgcn_mfma_f32_16x16x32_bf16(a_[u], b1_[u], acc1, 0, 0, 0);
          int nk = kt + 4 + u;
          if (nk < 64) { a_[u] = Ap[nk*64]; b0_[u] = Bp0[nk*64]; b1_[u] = Bp1[nk*64]; }
        }
      }

      const bool lastg = (s == S_ - 1) && (st == 3);
      const float wk = (st == 0 || st == 3) ? (1.0f / 6.0f) : (1.0f / 3.0f);
#pragma unroll
      for (int j = 0; j < 8; ++j) {
        int r = j & 3;
        float z = (j < 4) ? acc0[r] : acc1[r];
        float pre = z + bf2f((unsigned short)inpv[j]);
        float y = tanhf(pre);
        float k = y - an[j];                 // f(a) = -a + tanh(a W^T + inp)
        hacc[j] = (st == 0) ? (h[j] + wk * k) : (hacc[j] + wk * k);
        float anext;
        if (st == 3) { h[j] = hacc[j]; anext = h[j]; }
        else         { anext = h[j] + ((st == 2) ? 1.0f : 0.5f) * k; }
        an[j] = anext;
        if (!lastg) {
          WB[woff[j]] = f2bf(anext);
        } else {
          int row = 32 * rb + 16 * wr + ((l >> 4) << 2) + r;
          int col = 64 * rh + 32 * wc + 16 * (j >> 2) + (l & 15);
          h_out[(size_t)row * H_ + col] = h[j];
        }
      }
      if (!lastg) rb_barrier(cg, (unsigned)(s * 4 + st + 2));
    }
  }
}

// ---------------------------------------------------------------------------
// out[b][o] = h[b][:] @ W_dec[o][:] + b_dec[o]   (f32 vector, small)
// ---------------------------------------------------------------------------
__global__ void __launch_bounds__(256) decode_kernel(const float* __restrict__ h,
                                                     const float* __restrict__ W_dec,
                                                     const float* __restrict__ b_dec,
                                                     float* __restrict__ out) {
  __shared__ float hs[H_];
  int b = blockIdx.x, tid = threadIdx.x;
  for (int i = tid; i < H_; i += 256) hs[i] = h[(size_t)b * H_ + i];
  __syncthreads();
  int w = tid >> 6, l = tid & 63;
  for (int oi = 0; oi < 64; ++oi) {
    int o = w * 64 + oi;
    const float* wp = W_dec + (size_t)o * H_;
    float sum = 0.f;
#pragma unroll
    for (int c = 0; c < 32; ++c) sum += hs[c * 64 + l] * wp[c * 64 + l];
#pragma unroll
    for (int off = 32; off; off >>= 1) sum += __shfl_down(sum, off, 64);
    if (l == 0) out[(size_t)b * O_ + o] = sum + b_dec[o];
  }
}

// ---------------------------------------------------------------------------
extern "C" void kernel_launch(void* const* d_in, const int* in_sizes, int n_in,
                              void* d_out, int out_size, void* d_ws, size_t ws_size,
                              hipStream_t stream) {
  const float* x     = (const float*)d_in[0];
  const float* W_rec = (const float*)d_in[1];
  const float* W_in  = (const float*)d_in[2];
  const float* b_in  = (const float*)d_in[3];
  const float* W_dec = (const float*)d_in[4];
  const float* b_dec = (const float*)d_in[5];
  float* out = (float*)d_out;

  char* ws = (char*)d_ws;
  size_t off = 0;
  short8* w_frag = (short8*)(ws + off);            off += (size_t)H_ * H_ * 2;        // 8 MB
  short8* inp_f  = (short8*)(ws + off);            off += (size_t)S_ * B_ * H_ * 2;   // 128 MB
  unsigned short* a16_0 = (unsigned short*)(ws + off); off += (size_t)B_ * H_ * 2;    // 1 MB
  unsigned short* a16_1 = (unsigned short*)(ws + off); off += (size_t)B_ * H_ * 2;    // 1 MB
  float* h_ws = (float*)(ws + off);                off += (size_t)B_ * H_ * 4;        // 2 MB
  unsigned* cnt = (unsigned*)(ws + off);           off += 8 * 32 * 4;                 // 1 KB

  hipMemsetAsync(cnt, 0, 8 * 32 * 4, stream);
  prep_w<<<dim3((H_ / 16) * (H_ / 32) * 64 / 256), dim3(256), 0, stream>>>(W_rec, w_frag);
  inp_kernel<<<dim3(S_ * 256), dim3(256), 0, stream>>>(x, W_in, b_in, inp_f);

  void* args[6] = { (void*)&w_frag, (void*)&inp_f, (void*)&a16_0,
                    (void*)&a16_1, (void*)&h_ws, (void*)&cnt };
  hipError_t ce = hipLaunchCooperativeKernel((const void*)rnn_main, dim3(256), dim3(256),
                                             (void**)args, 0, stream);
  if (ce != hipSuccess) {
    // fallback: plain launch (256 wgs / 256 CUs, no LDS -> co-resident)
    rnn_main<<<dim3(256), dim3(256), 0, stream>>>(w_frag, inp_f, a16_0, a16_1, h_ws, cnt);
  }

  decode_kernel<<<dim3(B_), dim3(256), 0, stream>>>(h_ws, W_dec, b_dec, out);
}

// Round 2
// 19008.072 us; speedup vs baseline: 1.6467x; 1.6467x over previous
//
#include <hip/hip_runtime.h>
#include <hip/hip_bf16.h>

typedef __attribute__((ext_vector_type(8))) short short8;
typedef __attribute__((ext_vector_type(4))) float f32x4;

#define B_ 256
#define S_ 128
#define I_ 256
#define H_ 2048
#define O_ 256

#define SMEM_BYTES (131072 + 24576)   // 128 KB W + 24 KB reduce

__device__ __forceinline__ unsigned short f2bf(float f) {
  union { float f; unsigned u; } v; v.f = f;
  unsigned u = v.u;
  unsigned r = (u + 0x7FFFu + ((u >> 16) & 1u)) >> 16;  // RNE
  return (unsigned short)r;
}
__device__ __forceinline__ float bf2f(unsigned short u) {
  union { unsigned u; float f; } v; v.u = ((unsigned)u) << 16;
  return v.f;
}
__device__ __forceinline__ short8 cvt8(const float* p) {
  const f32x4* q = (const f32x4*)p;
  f32x4 a = q[0], b = q[1];
  short8 r;
  r[0]=(short)f2bf(a[0]); r[1]=(short)f2bf(a[1]); r[2]=(short)f2bf(a[2]); r[3]=(short)f2bf(a[3]);
  r[4]=(short)f2bf(b[0]); r[5]=(short)f2bf(b[1]); r[6]=(short)f2bf(b[2]); r[7]=(short)f2bf(b[3]);
  return r;
}

// ---------------------------------------------------------------------------
// Pack W_rec (f32 [H][H]) into MFMA B-fragment-major bf16:
// w_frag[nb][kt][lane][j] = W_rec[16*nb + (lane&15)][32*kt + 8*(lane>>4) + j]
// ---------------------------------------------------------------------------
__global__ void __launch_bounds__(256) prep_w(const float* __restrict__ W_rec,
                                              short8* __restrict__ w_frag) {
  int idx = blockIdx.x * 256 + threadIdx.x;      // 0 .. 128*64*64-1
  int l  = idx & 63;
  int kt = (idx >> 6) & 63;
  int nb = idx >> 12;
  int n  = nb * 16 + (l & 15);
  int k0 = kt * 32 + ((l >> 4) * 8);
  w_frag[idx] = cvt8(W_rec + (size_t)n * H_ + k0);
}

// ---------------------------------------------------------------------------
// inp[s][b][h] = x[b][s][:] @ W_in[h][:] + b_in[h], bf16, ownership-linear.
// ---------------------------------------------------------------------------
__global__ void __launch_bounds__(256) inp_kernel(const float* __restrict__ x,
                                                  const float* __restrict__ W_in,
                                                  const float* __restrict__ b_in,
                                                  short8* __restrict__ inp_f) {
  int bid = blockIdx.x;             // 0 .. 128*256-1
  int s   = bid >> 8;
  int sub = bid & 255;
  int rh  = sub >> 3, rb = sub & 7;
  int tid = threadIdx.x;
  int w = tid >> 6, l = tid & 63;
  int wr = w >> 1, wc = w & 1;

  int brow = 32 * rb + 16 * wr + (l & 15);
  int h0   = 64 * rh + 32 * wc + (l & 15);
  const float* xp  = x   + ((size_t)brow * S_ + s) * I_ + ((l >> 4) * 8);
  const float* wp0 = W_in + (size_t)h0 * I_        + ((l >> 4) * 8);
  const float* wp1 = W_in + (size_t)(h0 + 16) * I_ + ((l >> 4) * 8);

  f32x4 acc0 = {0.f,0.f,0.f,0.f}, acc1 = {0.f,0.f,0.f,0.f};
#pragma unroll
  for (int kt = 0; kt < 8; ++kt) {
    short8 af  = cvt8(xp  + kt * 32);
    short8 bf0 = cvt8(wp0 + kt * 32);
    short8 bf1 = cvt8(wp1 + kt * 32);
    acc0 = __builtin_amdgcn_mfma_f32_16x16x32_bf16(af, bf0, acc0, 0, 0, 0);
    acc1 = __builtin_amdgcn_mfma_f32_16x16x32_bf16(af, bf1, acc1, 0, 0, 0);
  }
  short8 outv;
#pragma unroll
  for (int j = 0; j < 8; ++j) {
    int nb = j >> 2, r = j & 3;
    int col = 64 * rh + 32 * wc + 16 * nb + (l & 15);
    float v = ((nb ? acc1 : acc0)[r]) + b_in[col];
    outv[j] = (short)f2bf(v);
  }
  inp_f[(size_t)bid * 256 + tid] = outv;
}

// ---------------------------------------------------------------------------
// Persistent RNN kernel. 256 wgs x 256 thr, 1 wg/CU.
// wg tile: 32 batch-rows (rb=bid&7) x 64 hidden-cols (rh=bid>>3).
// W tile (256 KB) lives ON-CHIP: nb{0,1} split-K in regs (128 VGPR/lane),
// nb{2,3} full-K in LDS (128 KB) -> immune to the per-stage L2 invalidate.
// Each wave computes a 16-kt K-slice of ALL 8 output tiles; 24 KB LDS
// reduction combines the 4 partial sums; ownership/epilogue unchanged.
// ---------------------------------------------------------------------------
__device__ __forceinline__ void rb_barrier(unsigned* __restrict__ cg, unsigned epoch) {
  __threadfence();          // release all this block's prior stores (agent)
  __syncthreads();
  if (threadIdx.x == 0) {
    __hip_atomic_fetch_add(cg, 1u, __ATOMIC_RELEASE, __HIP_MEMORY_SCOPE_AGENT);
    unsigned target = epoch * 32u;
    while (__hip_atomic_load(cg, __ATOMIC_RELAXED, __HIP_MEMORY_SCOPE_AGENT) < target) {
      __builtin_amdgcn_s_sleep(1);
    }
    __threadfence();        // acquire
  }
  __syncthreads();
}

__global__ void __launch_bounds__(256, 1) rnn_main(
    const short8* __restrict__ w_frag,
    const short8* __restrict__ inp_f,
    unsigned short* __restrict__ a16_0,
    unsigned short* __restrict__ a16_1,
    float* __restrict__ h_out,
    unsigned* __restrict__ cnt)
{
  extern __shared__ char smem[];
  short8* Wlds = (short8*)smem;                 // [2][64][64] short8 = 128 KB
  f32x4*  red  = (f32x4*)(smem + 131072);       // [4][6][64] f32x4  = 24 KB

  const int bid = blockIdx.x;
  const int rb = bid & 7, rh = bid >> 3;
  const int tid = threadIdx.x;
  const int w = tid >> 6, l = tid & 63;
  const int wr = w >> 1, wc = w & 1;
  const int kts = 16 * w;                   // this wave's kt slice start
  const int t0 = wr * 4 + 2 * wc;           // first owned tile (of 8)
  const int mb_g = 2 * rb + wr;
  const int ktw  = 2 * rh + wc;

  // ---- one-time W staging -------------------------------------------------
  {
    const short8* src = w_frag + (size_t)(4 * rh + 2) * 4096;
    for (int f = tid; f < 8192; f += 256) Wlds[f] = src[f];
  }
  short8 Wreg[2][16];
#pragma unroll
  for (int n = 0; n < 2; ++n)
#pragma unroll
    for (int i = 0; i < 16; ++i)
      Wreg[n][i] = w_frag[((size_t)(4 * rh + n) * 64 + kts + i) * 64 + l];

  const int off0 = (2 * rb) * 4096 + kts * 64 + l;   // A base (m=0), m=1 at +4096
  const short8* A0 = (const short8*)a16_0 + off0;
  const short8* A1 = (const short8*)a16_1 + off0;

  // write offsets (ushort units) of this thread's 8 owned elements
  int woff[8];
#pragma unroll
  for (int j = 0; j < 8; ++j) {
    int nb = j >> 2, r = j & 3;
    int lp = (2 * nb + ((l & 15) >> 3)) * 16 + ((l >> 4) * 4 + r);
    woff[j] = ((mb_g * 64 + ktw) * 64 + lp) * 8 + (l & 7);
  }

  float h[8], hacc[8], an[8];
#pragma unroll
  for (int j = 0; j < 8; ++j) { h[j] = 0.f; hacc[j] = 0.f; an[j] = 0.f; }
#pragma unroll
  for (int j = 0; j < 8; ++j) a16_0[woff[j]] = 0;   // h0 = 0 into buffer 0

  unsigned* cg = cnt + rb * 32;            // 128B-separated counters
  rb_barrier(cg, 1);

#pragma unroll 1
  for (int s = 0; s < S_; ++s) {
    short8 inpv = inp_f[((size_t)s * 256 + bid) * 256 + tid];
#pragma unroll 2
    for (int st = 0; st < 4; ++st) {
      const short8* Ap = (st & 1) ? A1 : A0;          // read buf[st&1]
      unsigned short* WB = (st & 1) ? a16_0 : a16_1;  // write the other

      f32x4 acc[2][4];
#pragma unroll
      for (int m = 0; m < 2; ++m)
#pragma unroll
        for (int n = 0; n < 4; ++n) acc[m][n] = (f32x4){0.f,0.f,0.f,0.f};

      // depth-8 A prefetch; each A fragment feeds 4 MFMAs (nb=0..3)
      short8 a0_[8], a1_[8];
#pragma unroll
      for (int u = 0; u < 8; ++u) { a0_[u] = Ap[u * 64]; a1_[u] = Ap[4096 + u * 64]; }
#pragma unroll
      for (int i = 0; i < 16; ++i) {
        short8 a0 = a0_[i & 7], a1 = a1_[i & 7];
        if (i < 8) { a0_[i] = Ap[(i + 8) * 64]; a1_[i] = Ap[4096 + (i + 8) * 64]; }
        short8 b2 = Wlds[(kts + i) * 64 + l];
        short8 b3 = Wlds[(64 + kts + i) * 64 + l];
        acc[0][0] = __builtin_amdgcn_mfma_f32_16x16x32_bf16(a0, Wreg[0][i], acc[0][0], 0, 0, 0);
        acc[0][1] = __builtin_amdgcn_mfma_f32_16x16x32_bf16(a0, Wreg[1][i], acc[0][1], 0, 0, 0);
        acc[0][2] = __builtin_amdgcn_mfma_f32_16x16x32_bf16(a0, b2,         acc[0][2], 0, 0, 0);
        acc[0][3] = __builtin_amdgcn_mfma_f32_16x16x32_bf16(a0, b3,         acc[0][3], 0, 0, 0);
        acc[1][0] = __builtin_amdgcn_mfma_f32_16x16x32_bf16(a1, Wreg[0][i], acc[1][0], 0, 0, 0);
        acc[1][1] = __builtin_amdgcn_mfma_f32_16x16x32_bf16(a1, Wreg[1][i], acc[1][1], 0, 0, 0);
        acc[1][2] = __builtin_amdgcn_mfma_f32_16x16x32_bf16(a1, b2,         acc[1][2], 0, 0, 0);
        acc[1][3] = __builtin_amdgcn_mfma_f32_16x16x32_bf16(a1, b3,         acc[1][3], 0, 0, 0);
      }

      // ---- 4-way split-K reduction through LDS ----------------------------
#pragma unroll
      for (int t = 0; t < 8; ++t) {
        if (t == t0 || t == t0 + 1) continue;
        int p = (t > t0 + 1) ? t - 2 : t;
        red[(w * 6 + p) * 64 + l] = acc[t >> 2][t & 3];
      }
      __syncthreads();
      f32x4 z0 = acc[wr][2 * wc], z1 = acc[wr][2 * wc + 1];
#pragma unroll
      for (int v = 0; v < 4; ++v) {
        if (v == w) continue;
        int o = (v >> 1) * 4 + 2 * (v & 1);
        int p0 = (t0 > o + 1) ? t0 - 2 : t0;
        z0 += red[(v * 6 + p0) * 64 + l];
        z1 += red[(v * 6 + p0 + 1) * 64 + l];
      }

      // ---- RK4 epilogue (ownership identical to proven round-1 kernel) ---
      const bool lastg = (s == S_ - 1) && (st == 3);
      const float wk = (st == 0 || st == 3) ? (1.0f / 6.0f) : (1.0f / 3.0f);
#pragma unroll
      for (int j = 0; j < 8; ++j) {
        int r = j & 3;
        float z = (j < 4) ? z0[r] : z1[r];
        float pre = z + bf2f((unsigned short)inpv[j]);
        float y = tanhf(pre);
        float k = y - an[j];                 // f(a) = -a + tanh(a W^T + inp)
        hacc[j] = (st == 0) ? (h[j] + wk * k) : (hacc[j] + wk * k);
        float anext;
        if (st == 3) { h[j] = hacc[j]; anext = h[j]; }
        else         { anext = h[j] + ((st == 2) ? 1.0f : 0.5f) * k; }
        an[j] = anext;
        if (!lastg) {
          WB[woff[j]] = f2bf(anext);
        } else {
          int row = 32 * rb + 16 * wr + ((l >> 4) << 2) + r;
          int col = 64 * rh + 32 * wc + 16 * (j >> 2) + (l & 15);
          h_out[(size_t)row * H_ + col] = h[j];
        }
      }
      if (!lastg) rb_barrier(cg, (unsigned)(s * 4 + st + 2));
    }
  }
}

// ---------------------------------------------------------------------------
// out[b][o] = h[b][:] @ W_dec[o][:] + b_dec[o]   (f32 vector, small)
// ---------------------------------------------------------------------------
__global__ void __launch_bounds__(256) decode_kernel(const float* __restrict__ h,
                                                     const float* __restrict__ W_dec,
                                                     const float* __restrict__ b_dec,
                                                     float* __restrict__ out) {
  __shared__ float hs[H_];
  int b = blockIdx.x, tid = threadIdx.x;
  for (int i = tid; i < H_; i += 256) hs[i] = h[(size_t)b * H_ + i];
  __syncthreads();
  int w = tid >> 6, l = tid & 63;
  for (int oi = 0; oi < 64; ++oi) {
    int o = w * 64 + oi;
    const float* wp = W_dec + (size_t)o * H_;
    float sum = 0.f;
#pragma unroll
    for (int c = 0; c < 32; ++c) sum += hs[c * 64 + l] * wp[c * 64 + l];
#pragma unroll
    for (int off = 32; off; off >>= 1) sum += __shfl_down(sum, off, 64);
    if (l == 0) out[(size_t)b * O_ + o] = sum + b_dec[o];
  }
}

// ---------------------------------------------------------------------------
extern "C" void kernel_launch(void* const* d_in, const int* in_sizes, int n_in,
                              void* d_out, int out_size, void* d_ws, size_t ws_size,
                              hipStream_t stream) {
  const float* x     = (const float*)d_in[0];
  const float* W_rec = (const float*)d_in[1];
  const float* W_in  = (const float*)d_in[2];
  const float* b_in  = (const float*)d_in[3];
  const float* W_dec = (const float*)d_in[4];
  const float* b_dec = (const float*)d_in[5];
  float* out = (float*)d_out;

  char* ws = (char*)d_ws;
  size_t off = 0;
  short8* w_frag = (short8*)(ws + off);            off += (size_t)H_ * H_ * 2;        // 8 MB
  short8* inp_f  = (short8*)(ws + off);            off += (size_t)S_ * B_ * H_ * 2;   // 128 MB
  unsigned short* a16_0 = (unsigned short*)(ws + off); off += (size_t)B_ * H_ * 2;    // 1 MB
  unsigned short* a16_1 = (unsigned short*)(ws + off); off += (size_t)B_ * H_ * 2;    // 1 MB
  float* h_ws = (float*)(ws + off);                off += (size_t)B_ * H_ * 4;        // 2 MB
  unsigned* cnt = (unsigned*)(ws + off);           off += 8 * 32 * 4;                 // 1 KB

  hipMemsetAsync(cnt, 0, 8 * 32 * 4, stream);
  prep_w<<<dim3((H_ / 16) * (H_ / 32) * 64 / 256), dim3(256), 0, stream>>>(W_rec, w_frag);
  inp_kernel<<<dim3(S_ * 256), dim3(256), 0, stream>>>(x, W_in, b_in, inp_f);

  hipFuncSetAttribute((const void*)rnn_main,
                      hipFuncAttributeMaxDynamicSharedMemorySize, SMEM_BYTES);

  void* args[6] = { (void*)&w_frag, (void*)&inp_f, (void*)&a16_0,
                    (void*)&a16_1, (void*)&h_ws, (void*)&cnt };
  hipError_t ce = hipLaunchCooperativeKernel((const void*)rnn_main, dim3(256), dim3(256),
                                             (void**)args, SMEM_BYTES, stream);
  if (ce != hipSuccess) {
    rnn_main<<<dim3(256), dim3(256), SMEM_BYTES, stream>>>(w_frag, inp_f, a16_0, a16_1, h_ws, cnt);
  }

  decode_kernel<<<dim3(B_), dim3(256), 0, stream>>>(h_ws, W_dec, b_dec, out);
}

// Round 3
// 6203.838 us; speedup vs baseline: 5.0454x; 3.0639x over previous
//
#include <hip/hip_runtime.h>
#include <hip/hip_bf16.h>

typedef __attribute__((ext_vector_type(8))) short short8;
typedef __attribute__((ext_vector_type(4))) float f32x4;

#define B_ 256
#define S_ 128
#define I_ 256
#define H_ 2048
#define O_ 256

#define SMEM_BYTES (131072 + 24576)   // 128 KB W + 24 KB reduce

__device__ __forceinline__ unsigned short f2bf(float f) {
  union { float f; unsigned u; } v; v.f = f;
  unsigned u = v.u;
  unsigned r = (u + 0x7FFFu + ((u >> 16) & 1u)) >> 16;  // RNE
  return (unsigned short)r;
}
__device__ __forceinline__ float bf2f(unsigned short u) {
  union { unsigned u; float f; } v; v.u = ((unsigned)u) << 16;
  return v.f;
}
__device__ __forceinline__ short8 cvt8(const float* p) {
  const f32x4* q = (const f32x4*)p;
  f32x4 a = q[0], b = q[1];
  short8 r;
  r[0]=(short)f2bf(a[0]); r[1]=(short)f2bf(a[1]); r[2]=(short)f2bf(a[2]); r[3]=(short)f2bf(a[3]);
  r[4]=(short)f2bf(b[0]); r[5]=(short)f2bf(b[1]); r[6]=(short)f2bf(b[2]); r[7]=(short)f2bf(b[3]);
  return r;
}

// ---- L3-coherent (cross-XCD) access primitives: no fences, no wbl2/inv ----
__device__ __forceinline__ void st_u16_wt(unsigned short* p, unsigned v) {
  asm volatile("global_store_short %0, %1, off sc0 sc1" :: "v"(p), "v"(v) : "memory");
}
__device__ __forceinline__ void st_u32_wt(unsigned* p, unsigned v) {
  asm volatile("global_store_dword %0, %1, off sc0 sc1" :: "v"(p), "v"(v) : "memory");
}
__device__ __forceinline__ unsigned ld_u32_coh(const unsigned* p) {
  unsigned r;
  asm volatile("global_load_dword %0, %1, off sc0 sc1\n\ts_waitcnt vmcnt(0)"
               : "=v"(r) : "v"(p) : "memory");
  return r;
}
__device__ __forceinline__ short8 ld_b128_coh(const short8* p) {   // issue only, no wait
  short8 r;
  asm volatile("global_load_dwordx4 %0, %1, off sc0 sc1" : "=v"(r) : "v"(p) : "memory");
  return r;
}
__device__ __forceinline__ void wait_vm0() {
  asm volatile("s_waitcnt vmcnt(0)" ::: "memory");
}
__device__ __forceinline__ void flag_wait(const unsigned* fgrp, int lane31, unsigned e) {
  const unsigned* fp = fgrp + lane31;
  while (true) {
    unsigned v = ld_u32_coh(fp);
    if (!__any(v < e)) break;
  }
}

// ---------------------------------------------------------------------------
// Pack W_rec (f32 [H][H]) into MFMA B-fragment-major bf16.
// ---------------------------------------------------------------------------
__global__ void __launch_bounds__(256) prep_w(const float* __restrict__ W_rec,
                                              short8* __restrict__ w_frag) {
  int idx = blockIdx.x * 256 + threadIdx.x;      // 0 .. 128*64*64-1
  int l  = idx & 63;
  int kt = (idx >> 6) & 63;
  int nb = idx >> 12;
  int n  = nb * 16 + (l & 15);
  int k0 = kt * 32 + ((l >> 4) * 8);
  w_frag[idx] = cvt8(W_rec + (size_t)n * H_ + k0);
}

// ---------------------------------------------------------------------------
// inp[s][b][h] = x[b][s][:] @ W_in[h][:] + b_in[h], bf16, ownership-linear.
// ---------------------------------------------------------------------------
__global__ void __launch_bounds__(256) inp_kernel(const float* __restrict__ x,
                                                  const float* __restrict__ W_in,
                                                  const float* __restrict__ b_in,
                                                  short8* __restrict__ inp_f) {
  int bid = blockIdx.x;             // 0 .. 128*256-1
  int s   = bid >> 8;
  int sub = bid & 255;
  int rh  = sub >> 3, rb = sub & 7;
  int tid = threadIdx.x;
  int w = tid >> 6, l = tid & 63;
  int wr = w >> 1, wc = w & 1;

  int brow = 32 * rb + 16 * wr + (l & 15);
  int h0   = 64 * rh + 32 * wc + (l & 15);
  const float* xp  = x   + ((size_t)brow * S_ + s) * I_ + ((l >> 4) * 8);
  const float* wp0 = W_in + (size_t)h0 * I_        + ((l >> 4) * 8);
  const float* wp1 = W_in + (size_t)(h0 + 16) * I_ + ((l >> 4) * 8);

  f32x4 acc0 = {0.f,0.f,0.f,0.f}, acc1 = {0.f,0.f,0.f,0.f};
#pragma unroll
  for (int kt = 0; kt < 8; ++kt) {
    short8 af  = cvt8(xp  + kt * 32);
    short8 bf0 = cvt8(wp0 + kt * 32);
    short8 bf1 = cvt8(wp1 + kt * 32);
    acc0 = __builtin_amdgcn_mfma_f32_16x16x32_bf16(af, bf0, acc0, 0, 0, 0);
    acc1 = __builtin_amdgcn_mfma_f32_16x16x32_bf16(af, bf1, acc1, 0, 0, 0);
  }
  short8 outv;
#pragma unroll
  for (int j = 0; j < 8; ++j) {
    int nb = j >> 2, r = j & 3;
    int col = 64 * rh + 32 * wc + 16 * nb + (l & 15);
    float v = ((nb ? acc1 : acc0)[r]) + b_in[col];
    outv[j] = (short)f2bf(v);
  }
  inp_f[(size_t)bid * 256 + tid] = outv;
}

// ---------------------------------------------------------------------------
// Persistent RNN kernel. 256 wgs x 256 thr, 1 wg/CU.
// wg tile: 32 batch-rows (rb=bid&7) x 64 hidden-cols (rh=bid>>3).
// W on-chip (128 VGPR/lane split-K + 128 KB LDS). Cross-wg communication
// flows write-through to L3 (sc0 sc1); sync via per-wg monotonic epoch
// flags, no atomics, no threadfence, no L2 writeback/invalidate.
// ---------------------------------------------------------------------------
__global__ void __launch_bounds__(256, 1) rnn_main(
    const short8* __restrict__ w_frag,
    const short8* __restrict__ inp_f,
    unsigned short* __restrict__ a16_0,
    unsigned short* __restrict__ a16_1,
    float* __restrict__ h_out,
    unsigned* __restrict__ flags)
{
  extern __shared__ char smem[];
  short8* Wlds = (short8*)smem;                 // [2][64][64] short8 = 128 KB
  f32x4*  red  = (f32x4*)(smem + 131072);       // [4][6][64] f32x4  = 24 KB

  const int bid = blockIdx.x;
  const int rb = bid & 7, rh = bid >> 3;
  const int tid = threadIdx.x;
  const int w = tid >> 6, l = tid & 63;
  const int wr = w >> 1, wc = w & 1;
  const int kts = 16 * w;                   // this wave's kt slice start
  const int t0 = wr * 4 + 2 * wc;           // first owned tile (of 8)
  const int mb_g = 2 * rb + wr;
  const int ktw  = 2 * rh + wc;

  // ---- one-time W staging -------------------------------------------------
  {
    const short8* src = w_frag + (size_t)(4 * rh + 2) * 4096;
    for (int f = tid; f < 8192; f += 256) Wlds[f] = src[f];
  }
  short8 Wreg[2][16];
#pragma unroll
  for (int n = 0; n < 2; ++n)
#pragma unroll
    for (int i = 0; i < 16; ++i)
      Wreg[n][i] = w_frag[((size_t)(4 * rh + n) * 64 + kts + i) * 64 + l];

  const int off0 = (2 * rb) * 4096 + kts * 64 + l;   // A base (m=0); m=1 at +4096
  const short8* A0 = (const short8*)a16_0 + off0;
  const short8* A1 = (const short8*)a16_1 + off0;

  // write offsets (ushort units) of this thread's 8 owned elements
  int woff[8];
#pragma unroll
  for (int j = 0; j < 8; ++j) {
    int nb = j >> 2, r = j & 3;
    int lp = (2 * nb + ((l & 15) >> 3)) * 16 + ((l >> 4) * 4 + r);
    woff[j] = ((mb_g * 64 + ktw) * 64 + lp) * 8 + (l & 7);
  }

  float h[8], hacc[8], an[8];
#pragma unroll
  for (int j = 0; j < 8; ++j) { h[j] = 0.f; hacc[j] = 0.f; an[j] = 0.f; }

  // h0 = 0: publish zeros into buffer 0 (write-through), then epoch-1 barrier
#pragma unroll
  for (int j = 0; j < 8; ++j) st_u16_wt(a16_0 + woff[j], 0u);
  wait_vm0();
  __syncthreads();
  unsigned* fgrp = flags + rb * 32;
  if (tid == 0) st_u32_wt(fgrp + rh, 1u);
  flag_wait(fgrp, l & 31, 1u);
  __builtin_amdgcn_sched_barrier(0);

#pragma unroll 1
  for (int s = 0; s < S_; ++s) {
    short8 inpv = inp_f[((size_t)s * 256 + bid) * 256 + tid];
#pragma unroll 2
    for (int st = 0; st < 4; ++st) {
      const short8* Ap = (st & 1) ? A1 : A0;          // read buf[st&1]
      unsigned short* WB = (st & 1) ? a16_0 : a16_1;  // write the other

      f32x4 acc[2][4];
#pragma unroll
      for (int m = 0; m < 2; ++m)
#pragma unroll
        for (int n = 0; n < 4; ++n) acc[m][n] = (f32x4){0.f,0.f,0.f,0.f};

      // ---- A loads: two 16-fragment batches, L3-coherent, issue-ahead ----
      short8 am0[16], am1[16];
#pragma unroll
      for (int i = 0; i < 16; ++i) am0[i] = ld_b128_coh(Ap + i * 64);
      wait_vm0();
      __builtin_amdgcn_sched_barrier(0);
#pragma unroll
      for (int i = 0; i < 16; ++i) am1[i] = ld_b128_coh(Ap + 4096 + i * 64);
      // compute m=0 while m=1 batch is in flight
#pragma unroll
      for (int i = 0; i < 16; ++i) {
        short8 b2 = Wlds[(kts + i) * 64 + l];
        short8 b3 = Wlds[(64 + kts + i) * 64 + l];
        acc[0][0] = __builtin_amdgcn_mfma_f32_16x16x32_bf16(am0[i], Wreg[0][i], acc[0][0], 0, 0, 0);
        acc[0][1] = __builtin_amdgcn_mfma_f32_16x16x32_bf16(am0[i], Wreg[1][i], acc[0][1], 0, 0, 0);
        acc[0][2] = __builtin_amdgcn_mfma_f32_16x16x32_bf16(am0[i], b2,         acc[0][2], 0, 0, 0);
        acc[0][3] = __builtin_amdgcn_mfma_f32_16x16x32_bf16(am0[i], b3,         acc[0][3], 0, 0, 0);
      }
      wait_vm0();
      __builtin_amdgcn_sched_barrier(0);
#pragma unroll
      for (int i = 0; i < 16; ++i) {
        short8 b2 = Wlds[(kts + i) * 64 + l];
        short8 b3 = Wlds[(64 + kts + i) * 64 + l];
        acc[1][0] = __builtin_amdgcn_mfma_f32_16x16x32_bf16(am1[i], Wreg[0][i], acc[1][0], 0, 0, 0);
        acc[1][1] = __builtin_amdgcn_mfma_f32_16x16x32_bf16(am1[i], Wreg[1][i], acc[1][1], 0, 0, 0);
        acc[1][2] = __builtin_amdgcn_mfma_f32_16x16x32_bf16(am1[i], b2,         acc[1][2], 0, 0, 0);
        acc[1][3] = __builtin_amdgcn_mfma_f32_16x16x32_bf16(am1[i], b3,         acc[1][3], 0, 0, 0);
      }

      // ---- 4-way split-K reduction through LDS ----------------------------
#pragma unroll
      for (int t = 0; t < 8; ++t) {
        if (t == t0 || t == t0 + 1) continue;
        int p = (t > t0 + 1) ? t - 2 : t;
        red[(w * 6 + p) * 64 + l] = acc[t >> 2][t & 3];
      }
      __syncthreads();
      f32x4 z0 = acc[wr][2 * wc], z1 = acc[wr][2 * wc + 1];
#pragma unroll
      for (int v = 0; v < 4; ++v) {
        if (v == w) continue;
        int o = (v >> 1) * 4 + 2 * (v & 1);
        int p0 = (t0 > o + 1) ? t0 - 2 : t0;
        z0 += red[(v * 6 + p0) * 64 + l];
        z1 += red[(v * 6 + p0 + 1) * 64 + l];
      }
      __syncthreads();   // red reused next stage

      // ---- RK4 epilogue (ownership identical to proven kernel) -----------
      const bool lastg = (s == S_ - 1) && (st == 3);
      const float wk = (st == 0 || st == 3) ? (1.0f / 6.0f) : (1.0f / 3.0f);
#pragma unroll
      for (int j = 0; j < 8; ++j) {
        int r = j & 3;
        float z = (j < 4) ? z0[r] : z1[r];
        float pre = z + bf2f((unsigned short)inpv[j]);
        float y = tanhf(pre);
        float k = y - an[j];                 // f(a) = -a + tanh(a W^T + inp)
        hacc[j] = (st == 0) ? (h[j] + wk * k) : (hacc[j] + wk * k);
        float anext;
        if (st == 3) { h[j] = hacc[j]; anext = h[j]; }
        else         { anext = h[j] + ((st == 2) ? 1.0f : 0.5f) * k; }
        an[j] = anext;
        if (!lastg) {
          st_u16_wt(WB + woff[j], (unsigned)f2bf(anext));
        } else {
          int row = 32 * rb + 16 * wr + ((l >> 4) << 2) + r;
          int col = 64 * rh + 32 * wc + 16 * (j >> 2) + (l & 15);
          h_out[(size_t)row * H_ + col] = h[j];
        }
      }
      if (!lastg) {
        wait_vm0();                    // publishes visible at L3
        __syncthreads();               // whole wg published
        unsigned e = (unsigned)(s * 4 + st + 2);
        if (tid == 0) st_u32_wt(fgrp + rh, e);
        flag_wait(fgrp, l & 31, e);    // every thread waits for all 32 wgs
        __builtin_amdgcn_sched_barrier(0);
      }
    }
  }
}

// ---------------------------------------------------------------------------
// out[b][o] = h[b][:] @ W_dec[o][:] + b_dec[o]   (f32 vector, small)
// ---------------------------------------------------------------------------
__global__ void __launch_bounds__(256) decode_kernel(const float* __restrict__ h,
                                                     const float* __restrict__ W_dec,
                                                     const float* __restrict__ b_dec,
                                                     float* __restrict__ out) {
  __shared__ float hs[H_];
  int b = blockIdx.x, tid = threadIdx.x;
  for (int i = tid; i < H_; i += 256) hs[i] = h[(size_t)b * H_ + i];
  __syncthreads();
  int w = tid >> 6, l = tid & 63;
  for (int oi = 0; oi < 64; ++oi) {
    int o = w * 64 + oi;
    const float* wp = W_dec + (size_t)o * H_;
    float sum = 0.f;
#pragma unroll
    for (int c = 0; c < 32; ++c) sum += hs[c * 64 + l] * wp[c * 64 + l];
#pragma unroll
    for (int off = 32; off; off >>= 1) sum += __shfl_down(sum, off, 64);
    if (l == 0) out[(size_t)b * O_ + o] = sum + b_dec[o];
  }
}

// ---------------------------------------------------------------------------
extern "C" void kernel_launch(void* const* d_in, const int* in_sizes, int n_in,
                              void* d_out, int out_size, void* d_ws, size_t ws_size,
                              hipStream_t stream) {
  const float* x     = (const float*)d_in[0];
  const float* W_rec = (const float*)d_in[1];
  const float* W_in  = (const float*)d_in[2];
  const float* b_in  = (const float*)d_in[3];
  const float* W_dec = (const float*)d_in[4];
  const float* b_dec = (const float*)d_in[5];
  float* out = (float*)d_out;

  char* ws = (char*)d_ws;
  size_t off = 0;
  short8* w_frag = (short8*)(ws + off);            off += (size_t)H_ * H_ * 2;        // 8 MB
  short8* inp_f  = (short8*)(ws + off);            off += (size_t)S_ * B_ * H_ * 2;   // 128 MB
  unsigned short* a16_0 = (unsigned short*)(ws + off); off += (size_t)B_ * H_ * 2;    // 1 MB
  unsigned short* a16_1 = (unsigned short*)(ws + off); off += (size_t)B_ * H_ * 2;    // 1 MB
  float* h_ws = (float*)(ws + off);                off += (size_t)B_ * H_ * 4;        // 2 MB
  unsigned* flags = (unsigned*)(ws + off);         off += 8 * 32 * 4;                 // 1 KB

  hipMemsetAsync(flags, 0, 8 * 32 * 4, stream);
  prep_w<<<dim3((H_ / 16) * (H_ / 32) * 64 / 256), dim3(256), 0, stream>>>(W_rec, w_frag);
  inp_kernel<<<dim3(S_ * 256), dim3(256), 0, stream>>>(x, W_in, b_in, inp_f);

  hipFuncSetAttribute((const void*)rnn_main,
                      hipFuncAttributeMaxDynamicSharedMemorySize, SMEM_BYTES);

  void* args[6] = { (void*)&w_frag, (void*)&inp_f, (void*)&a16_0,
                    (void*)&a16_1, (void*)&h_ws, (void*)&flags };
  hipError_t ce = hipLaunchCooperativeKernel((const void*)rnn_main, dim3(256), dim3(256),
                                             (void**)args, SMEM_BYTES, stream);
  if (ce != hipSuccess) {
    rnn_main<<<dim3(256), dim3(256), SMEM_BYTES, stream>>>(w_frag, inp_f, a16_0, a16_1, h_ws, flags);
  }

  decode_kernel<<<dim3(B_), dim3(256), 0, stream>>>(h_ws, W_dec, b_dec, out);
}